// Round 4
// baseline (1017.674 us; speedup 1.0000x reference)
//
#include <hip/hip_runtime.h>

#define NPTS   8192
#define CCH    32
#define LDIM   64
#define ODIM   128
#define KNN    16
#define QPB    16                  // queries per block (4 waves x 4)
#define NBLK   ((4 * NPTS) / QPB)  // 2048 blocks
#define NSTEP  (NPTS / 64)         // 128 candidate steps per wave

// Prologue: squared norms of all 32768 points into d_ws.
__global__ void sq_kernel(const float* __restrict__ x, float* __restrict__ sqg) {
    int i = blockIdx.x * 256 + threadIdx.x;
    const float4* p = (const float4*)(x + (size_t)i * CCH);
    float s = 0.f;
    #pragma unroll
    for (int k = 0; k < 8; ++k) {
        float4 v = p[k];
        s += v.x * v.x + v.y * v.y + v.z * v.z + v.w * v.w;
    }
    sqg[i] = s;
}

__global__ __launch_bounds__(256, 6)
void graph_layer_kernel(const float* __restrict__ x,
                        const float* __restrict__ sqg,
                        const float* __restrict__ Wl,
                        const float* __restrict__ bl,
                        const float* __restrict__ Wc,
                        const float* __restrict__ bc,
                        float* __restrict__ out)
{
    __shared__ int   kn[QPB * KNN];      // [16][16] neighbor idx
    __shared__ float pl[QPB * 33];       // pooled, +1 pad
    __shared__ float hh[QPB * 65];       // hidden, +1 pad

    const int tid  = threadIdx.x;
    const int lane = tid & 63;
    const int wu   = __builtin_amdgcn_readfirstlane(tid >> 6);  // uniform wave id
    const float INF = __builtin_inff();

    const int qb0 = blockIdx.x * QPB;
    const int b   = qb0 >> 13;
    const float* xb  = x   + (size_t)(b << 13) * CCH;
    const float* sqb = sqg + (b << 13);

    // wave-uniform query pointers -> scalar (s_load) accesses in the k-loop
    const float4* q0p = (const float4*)(x + (size_t)(qb0 + wu * 4 + 0) * CCH);
    const float4* q1p = (const float4*)(x + (size_t)(qb0 + wu * 4 + 1) * CCH);
    const float4* q2p = (const float4*)(x + (size_t)(qb0 + wu * 4 + 2) * CCH);
    const float4* q3p = (const float4*)(x + (size_t)(qb0 + wu * 4 + 3) * CCH);

    // distributed sorted-16: query g's list lives in lanes g*16..g*16+15
    float selk = INF;
    int   seli = 0;
    float T0 = INF, T1 = INF, T2 = INF, T3 = INF;

    auto sel_insert = [&](float key, float& Tref, int gsel, int cbase) {
        unsigned long long m = __ballot(key < Tref);
        if (m) {
            const bool ing = (lane >> 4) == gsel;
            do {
                int src = __ffsll(m) - 1;          // ascending lane = ascending idx
                float nk = __shfl(key, src);
                int   ni = cbase + src;
                float upk = __shfl_up(selk, 1);
                int   upi = __shfl_up(seli, 1);
                bool pme   = nk < selk;            // strict <: lower idx wins ties
                bool pprev = (nk < upk) && ((lane & 15) != 0);
                float rk = pme ? (pprev ? upk : nk) : selk;
                int   ri = pme ? (pprev ? upi : ni) : seli;
                if (ing) { selk = rk; seli = ri; }
                m &= (m - 1);
            } while (m);
            Tref = __shfl(selk, gsel * 16 + 15);   // new 16th-best threshold
        }
    };

    // ---- scan: each wave streams ALL 8192 candidates for its 4 queries ----
    #pragma unroll 1
    for (int t = 0; t < NSTEP; ++t) {
        const int c = t * 64 + lane;
        const float4* cp = (const float4*)(xb + (size_t)c * CCH);
        float4 c0 = cp[0], c1 = cp[1], c2 = cp[2], c3 = cp[3];
        float4 c4 = cp[4], c5 = cp[5], c6 = cp[6], c7 = cp[7];
        float sqv = sqb[c];

        float a0 = 0.f, a1 = 0.f, a2 = 0.f, a3 = 0.f;
        #pragma unroll
        for (int k = 0; k < 8; ++k) {
            float4 cv = (k == 0) ? c0 : (k == 1) ? c1 : (k == 2) ? c2 : (k == 3) ? c3
                      : (k == 4) ? c4 : (k == 5) ? c5 : (k == 6) ? c6 : c7;
            float4 qa = q0p[k], qb = q1p[k], qc = q2p[k], qd = q3p[k];
            a0 = fmaf(cv.x, qa.x, a0); a0 = fmaf(cv.y, qa.y, a0);
            a0 = fmaf(cv.z, qa.z, a0); a0 = fmaf(cv.w, qa.w, a0);
            a1 = fmaf(cv.x, qb.x, a1); a1 = fmaf(cv.y, qb.y, a1);
            a1 = fmaf(cv.z, qb.z, a1); a1 = fmaf(cv.w, qb.w, a1);
            a2 = fmaf(cv.x, qc.x, a2); a2 = fmaf(cv.y, qc.y, a2);
            a2 = fmaf(cv.z, qc.z, a2); a2 = fmaf(cv.w, qc.w, a2);
            a3 = fmaf(cv.x, qd.x, a3); a3 = fmaf(cv.y, qd.y, a3);
            a3 = fmaf(cv.z, qd.z, a3); a3 = fmaf(cv.w, qd.w, a3);
        }
        float k0 = fmaf(-2.f, a0, sqv);
        float k1 = fmaf(-2.f, a1, sqv);
        float k2 = fmaf(-2.f, a2, sqv);
        float k3 = fmaf(-2.f, a3, sqv);
        const int cbase = t * 64;
        sel_insert(k0, T0, 0, cbase);
        sel_insert(k1, T1, 1, cbase);
        sel_insert(k2, T2, 2, cbase);
        sel_insert(k3, T3, 3, cbase);
    }

    // ---- write knn indices (each lane holds exactly one (query, rank)) ----
    kn[(wu * 4 + (lane >> 4)) * KNN + (lane & 15)] = seli;
    __syncthreads();

    // ---- gather + max-pool: thread -> (q = tid>>4, channels 2*(tid&15)) ----
    {
        int q = tid >> 4, c2 = (tid & 15) * 2;
        float m0 = -INF, m1 = -INF;
        #pragma unroll
        for (int k = 0; k < KNN; ++k) {
            int j = kn[q * KNN + k];
            float2 v = *(const float2*)(xb + (size_t)j * CCH + c2);
            m0 = fmaxf(m0, v.x); m1 = fmaxf(m1, v.y);
        }
        pl[q * 33 + c2] = m0; pl[q * 33 + c2 + 1] = m1;
    }
    __syncthreads();

    // ---- linear 32->64 ----
    {
        int l = tid & 63, qg = tid >> 6;
        #pragma unroll 1
        for (int q = qg; q < QPB; q += 4) {
            float acc = bl[l];
            #pragma unroll
            for (int c = 0; c < CCH; ++c)
                acc = fmaf(pl[q * 33 + c], Wl[c * LDIM + l], acc);
            hh[q * 65 + l] = acc;
        }
    }
    __syncthreads();

    // ---- conv1x1 64->128 + relu ----
    {
        int o = tid & 127, qh = tid >> 7;
        #pragma unroll 1
        for (int q = qh; q < QPB; q += 2) {
            float acc = bc[o];
            #pragma unroll
            for (int l = 0; l < LDIM; ++l)
                acc = fmaf(hh[q * 65 + l], Wc[l * ODIM + o], acc);
            out[(size_t)(qb0 + q) * ODIM + o] = fmaxf(acc, 0.f);
        }
    }
}

extern "C" void kernel_launch(void* const* d_in, const int* in_sizes, int n_in,
                              void* d_out, int out_size, void* d_ws, size_t ws_size,
                              hipStream_t stream) {
    const float* x  = (const float*)d_in[0];
    const float* Wl = (const float*)d_in[1];
    const float* bl = (const float*)d_in[2];
    const float* Wc = (const float*)d_in[3];
    const float* bc = (const float*)d_in[4];
    float* out = (float*)d_out;
    float* sqf = (float*)d_ws;                 // 32768 floats = 128 KB
    (void)in_sizes; (void)n_in; (void)out_size; (void)ws_size;

    hipLaunchKernelGGL(sq_kernel, dim3((4 * NPTS) / 256), dim3(256), 0, stream, x, sqf);
    hipLaunchKernelGGL(graph_layer_kernel, dim3(NBLK), dim3(256), 0, stream,
                       x, sqf, Wl, bl, Wc, bc, out);
}